// Round 1
// baseline (711.354 us; speedup 1.0000x reference)
//
#include <hip/hip_runtime.h>

#define H 128
#define INW 13
#define BATCH 262144
#define MT 64              // rows per LDS tile
#define LDK 168            // padded k-stride in shorts (336 B, chunk stride 21 = odd -> conflict-free b128)
#define KSTEPS 5           // K = 160 (128 h + 13 x + pad)
#define GRID 256
#define TPW (BATCH / MT / GRID)   // 16 tiles per workgroup

typedef __attribute__((ext_vector_type(8))) short bf16x8;
typedef __attribute__((ext_vector_type(4))) float f32x4;

struct Params {
  const float* x; const float* h; const float* c;
  const float* Wx[4]; const float* bx[4];
  const float* Wh[4]; const float* bh[4];
  float* out;
};

__device__ __forceinline__ unsigned short bf16_rne(float f) {
  unsigned u = __builtin_bit_cast(unsigned, f);
  u += 0x7FFFu + ((u >> 16) & 1u);
  return (unsigned short)(u >> 16);
}
__device__ __forceinline__ float bf16_to_f(unsigned short s) {
  unsigned u = ((unsigned)s) << 16;
  return __builtin_bit_cast(float, u);
}
__device__ __forceinline__ void split2(float f, unsigned short& hi, unsigned short& lo) {
  hi = bf16_rne(f);
  lo = bf16_rne(f - bf16_to_f(hi));
}
__device__ __forceinline__ float sigf(float x) {
  return __builtin_amdgcn_rcpf(1.0f + __expf(-x));
}
__device__ __forceinline__ float clamp1(float x) {
  return fminf(fmaxf(x, -1.0f), 1.0f);
}

__global__ __launch_bounds__(512, 2) void lstm_fused(Params p) {
  __shared__ __align__(16) unsigned short lds[2][2][MT][LDK]; // [buf][hi/lo][row][k] = 84 KiB

  const int tid  = threadIdx.x;
  const int lane = tid & 63;
  const int wave = tid >> 6;        // 0..7, owns output cols [wave*16, wave*16+16)
  const int l15  = lane & 15;
  const int lq   = lane >> 4;       // 0..3
  const int wcol = wave * 16 + l15; // output column 0..127 (also weight row within gate)
  const int koff = lq * 8;

  // ---- resident weight fragments: Wcat[g*128+wcol][k] split into bf16 hi/lo ----
  bf16x8 wfh[4][KSTEPS];
  bf16x8 wfl[4][KSTEPS];
  float  bias[4];
#pragma unroll
  for (int g = 0; g < 4; ++g) {
    const float* Wh = p.Wh[g];
    const float* Wx = p.Wx[g];
#pragma unroll
    for (int ks = 0; ks < KSTEPS; ++ks) {
      float w[8];
#pragma unroll
      for (int j = 0; j < 8; ++j) {
        if (ks < 4) {
          w[j] = Wh[wcol * H + ks * 32 + koff + j];
        } else {
          int kx = koff + j;
          w[j] = (kx < INW) ? Wx[wcol * INW + kx] : 0.0f;
        }
      }
      bf16x8 hi, lo;
#pragma unroll
      for (int j = 0; j < 8; ++j) {
        unsigned short a, b; split2(w[j], a, b);
        hi[j] = (short)a; lo[j] = (short)b;
      }
      wfh[g][ks] = hi; wfl[g][ks] = lo;
    }
    bias[g] = p.bx[g][wcol] + p.bh[g][wcol];
  }

  const long tile0 = (long)blockIdx.x * TPW;
  float4 hreg[4];
  float  xreg[4];

  auto issue_stage = [&](long t) {
    const long R = t * MT;
    const float4* h4 = reinterpret_cast<const float4*>(p.h);
#pragma unroll
    for (int i = 0; i < 4; ++i) {       // h: 64 rows x 128 f32, coalesced float4
      int idx = i * 512 + tid;
      int row = idx >> 5, c4 = idx & 31;
      hreg[i] = h4[(R + row) * (H / 4) + c4];
    }
#pragma unroll
    for (int i = 0; i < 4; ++i) {       // x cols 128..159 (13 real + zero pad)
      int idx = i * 512 + tid;
      int row = idx >> 5, cc = idx & 31;
      xreg[i] = (cc < INW) ? p.x[(R + row) * INW + cc] : 0.0f;
    }
  };

  auto write_stage = [&](int buf) {
#pragma unroll
    for (int i = 0; i < 4; ++i) {
      int idx = i * 512 + tid;
      int row = idx >> 5, c4 = idx & 31;
      unsigned short h0,h1,h2,h3,l0,l1,l2,l3;
      split2(hreg[i].x, h0, l0); split2(hreg[i].y, h1, l1);
      split2(hreg[i].z, h2, l2); split2(hreg[i].w, h3, l3);
      uint2 ph, pl;
      ph.x = (unsigned)h0 | ((unsigned)h1 << 16);
      ph.y = (unsigned)h2 | ((unsigned)h3 << 16);
      pl.x = (unsigned)l0 | ((unsigned)l1 << 16);
      pl.y = (unsigned)l2 | ((unsigned)l3 << 16);
      *reinterpret_cast<uint2*>(&lds[buf][0][row][c4 * 4]) = ph;
      *reinterpret_cast<uint2*>(&lds[buf][1][row][c4 * 4]) = pl;
    }
#pragma unroll
    for (int i = 0; i < 4; ++i) {
      int idx = i * 512 + tid;
      int row = idx >> 5, cc = idx & 31;
      unsigned short a, b; split2(xreg[i], a, b);
      lds[buf][0][row][H + cc] = a;
      lds[buf][1][row][H + cc] = b;
    }
  };

  issue_stage(tile0);
  write_stage(0);
  __syncthreads();

  float* o0 = p.out;
  float* o1 = p.out + (long)BATCH * H;
  float* o2 = p.out + 2L * (long)BATCH * H;

  for (int t = 0; t < TPW; ++t) {
    const long R  = (tile0 + t) * MT;
    const int buf = t & 1;

    // c_in prefetch for this tile (latency hidden under MFMA phase)
    float cin[4][4];
#pragma unroll
    for (int s = 0; s < 4; ++s)
#pragma unroll
      for (int q = 0; q < 4; ++q)
        cin[s][q] = p.c[(R + s * 16 + lq * 4 + q) * H + wcol];

    // issue next tile's global loads (consumed after the MFMA phase)
    if (t + 1 < TPW) issue_stage(tile0 + t + 1);

#pragma unroll
    for (int s = 0; s < 4; ++s) {
      const unsigned short* ah_base = &lds[buf][0][s * 16 + l15][koff];
      const unsigned short* al_base = &lds[buf][1][s * 16 + l15][koff];
      f32x4 acc[4];
#pragma unroll
      for (int g = 0; g < 4; ++g) { f32x4 v = {bias[g], bias[g], bias[g], bias[g]}; acc[g] = v; }
#pragma unroll
      for (int ks = 0; ks < KSTEPS; ++ks) {
        bf16x8 ah = *reinterpret_cast<const bf16x8*>(ah_base + ks * 32);
        bf16x8 al = *reinterpret_cast<const bf16x8*>(al_base + ks * 32);
#pragma unroll
        for (int g = 0; g < 4; ++g) {
          acc[g] = __builtin_amdgcn_mfma_f32_16x16x32_bf16(ah, wfh[g][ks], acc[g], 0, 0, 0);
          acc[g] = __builtin_amdgcn_mfma_f32_16x16x32_bf16(al, wfh[g][ks], acc[g], 0, 0, 0);
          acc[g] = __builtin_amdgcn_mfma_f32_16x16x32_bf16(ah, wfl[g][ks], acc[g], 0, 0, 0);
        }
      }
      // fused gate epilogue: C/D layout col=lane&15, row=lq*4+q  [m89-verified]
#pragma unroll
      for (int q = 0; q < 4; ++q) {
        float it = sigf(acc[0][q]);
        float ft = sigf(acc[1][q]);
        float gt = clamp1(acc[2][q]);
        float ot = sigf(acc[3][q]);
        float ct = ft * cin[s][q] + it * gt;
        float ht = ot * clamp1(ct);
        long row = R + s * 16 + lq * 4 + q;
        o0[row * H + wcol] = ht;
        o1[row * H + wcol] = ht;
        o2[row * H + wcol] = ct;
      }
    }

    if (t + 1 < TPW) write_stage(buf ^ 1); // write OTHER buffer; safe pre-barrier
    __syncthreads();                        // one barrier per tile
  }
}

extern "C" void kernel_launch(void* const* d_in, const int* in_sizes, int n_in,
                              void* d_out, int out_size, void* d_ws, size_t ws_size,
                              hipStream_t stream) {
  (void)in_sizes; (void)n_in; (void)d_ws; (void)ws_size; (void)out_size;
  Params p;
  p.x = (const float*)d_in[0];
  p.h = (const float*)d_in[1];
  p.c = (const float*)d_in[2];
  for (int g = 0; g < 4; ++g) {
    p.Wx[g] = (const float*)d_in[3 + 4 * g];
    p.bx[g] = (const float*)d_in[4 + 4 * g];
    p.Wh[g] = (const float*)d_in[5 + 4 * g];
    p.bh[g] = (const float*)d_in[6 + 4 * g];
  }
  p.out = (float*)d_out;
  hipLaunchKernelGGL(lstm_fused, dim3(GRID), dim3(512), 0, stream, p);
}